// Round 7
// baseline (98.181 us; speedup 1.0000x reference)
//
#include <hip/hip_runtime.h>

#define NPTS   8192
#define BLOCK  256
#define IB     64                  // distinct i's per block (shared by all 4 waves)
#define NSUB   4                   // j-subsplits per block = waves per block
#define JS     16                  // grid-level j splits
#define JTILE  (NPTS/(NSUB*JS))    // 128 j's per wave

// K = exp(-100*d2) = exp2(d2 * -100*log2(e))
#define NEG100_LOG2E  (-144.26950408889634f)

// out: [0..3N) = -dH/dq = +400*sum_j K*(pi.pj)*(qi-qj); [3N..6N) = dH/dp = 2*sum_j K*pj
__global__ __launch_bounds__(BLOCK, 8) void lddmm_hamilton_kernel(
    const float* __restrict__ mom,  // [N,3]
    const float* __restrict__ q,    // [N,3]
    float* __restrict__ out)        // [2,N,3]
{
    __shared__ float pr[NSUB * IB * 6];           // 6 KiB cross-wave partials

    const int tid  = threadIdx.x;
    const int ib   = blockIdx.x & (NPTS/IB - 1);  // 0..127
    const int jsg  = blockIdx.x >> 7;             // 0..15
    const int iloc = tid & 63;
    const int i    = ib * IB + iloc;
    // wave id forced into an SGPR so all j-addresses are provably wave-uniform
    const int jsub = __builtin_amdgcn_readfirstlane(tid >> 6);    // 0..3
    const int j0   = (jsg * NSUB + jsub) * JTILE;

    // per-i values (vector loads, coalesced across lanes)
    const float qix = q[3*i+0],  qiy = q[3*i+1],  qiz = q[3*i+2];
    const float pix = mom[3*i+0], piy = mom[3*i+1], piz = mom[3*i+2];

    float a0=0.f, a1=0.f, a2=0.f;   // sum K*(pi.pj)*(qi-qj)
    float m0=0.f, m1=0.f, m2=0.f;   // sum K*pj

    // wave-uniform j-stream: compiler emits s_load_dwordx* into SGPRs,
    // keeping the LDS and vector-memory pipes idle in the hot loop.
    const float* __restrict__ qj = q   + 3*j0;
    const float* __restrict__ pj = mom + 3*j0;

    #pragma unroll 8
    for (int t = 0; t < JTILE; ++t) {
        const float qjx = qj[3*t+0];
        const float qjy = qj[3*t+1];
        const float qjz = qj[3*t+2];
        const float pjx = pj[3*t+0];
        const float pjy = pj[3*t+1];
        const float pjz = pj[3*t+2];

        const float dx = qix - qjx;               // v_sub v,v,s
        const float dy = qiy - qjy;
        const float dz = qiz - qjz;
        const float d2 = dx*dx + dy*dy + dz*dz;   // mul + 2 fma
        const float K  = exp2f(d2 * NEG100_LOG2E);// v_mul(lit) + v_exp_f32
        const float dot = pix*pjx + piy*pjy + piz*pjz;  // mul + 2 fma (1 sgpr each)
        m0 += K * pjx;  m1 += K * pjy;  m2 += K * pjz;  // 3 fmac (1 sgpr each)
        const float w = K * dot;
        a0 += w * dx;  a1 += w * dy;  a2 += w * dz;     // 3 fmac
    }

    // stash per-wave partials
    {
      float r[6] = {a0,a1,a2,m0,m1,m2};
      #pragma unroll
      for (int c = 0; c < 6; ++c) pr[(jsub*IB + iloc)*6 + c] = r[c];
    }
    __syncthreads();

    // cross-wave reduce + one atomic per (i, component) per block
    #pragma unroll
    for (int pass = 0; pass < 2; ++pass) {
        const int t  = tid + pass * BLOCK;        // 0..511
        const int il = t >> 3;                    // 0..63
        const int c  = t & 7;                     // 0..7 (c>=6 idle)
        if (c < 6) {
            float s = 0.f;
            #pragma unroll
            for (int w2 = 0; w2 < NSUB; ++w2) s += pr[(w2*IB + il)*6 + c];
            const int ii = ib * IB + il;
            if (c < 3) atomicAdd(&out[3*ii + c],              400.0f * s);
            else       atomicAdd(&out[3*NPTS + 3*ii + (c-3)],   2.0f * s);
        }
    }
}

extern "C" void kernel_launch(void* const* d_in, const int* in_sizes, int n_in,
                              void* d_out, int out_size, void* d_ws, size_t ws_size,
                              hipStream_t stream) {
    const float* mom = (const float*)d_in[0];   // setup_inputs order: mom first
    const float* q   = (const float*)d_in[1];   // then control_points
    float* out = (float*)d_out;

    // d_out is re-poisoned to 0xAA before every timed launch; atomics need zeros.
    hipMemsetAsync(out, 0, (size_t)out_size * sizeof(float), stream);

    const dim3 grid((NPTS/IB) * JS);            // 128 * 16 = 2048 blocks, 8/CU
    lddmm_hamilton_kernel<<<grid, BLOCK, 0, stream>>>(mom, q, out);
}

// Round 9
// 92.343 us; speedup vs baseline: 1.0632x; 1.0632x over previous
//
#include <hip/hip_runtime.h>

#define NPTS   8192
#define BLOCK  256
#define IR     4                    // i's per thread (register tile)
#define IBSZ   (64*IR)              // 256 distinct i's per block
#define NIB    (NPTS/IBSZ)          // 32 i-blocks
#define JS     32                   // grid-level j splits
#define JBLK   (NPTS/JS)            // 256 j's staged per block
#define NPAIR  (JBLK/2)             // 128 packed pairs
#define WPAIR  (NPAIR/4)            // 32 pairs per wave (64 j's)

// K = exp(-100*d2) = exp2(d2 * -100*log2(e))
#define NEG100_LOG2E  (-144.26950408889634f)

#if __has_builtin(__builtin_amdgcn_exp2f)
#define EXP2(x) __builtin_amdgcn_exp2f(x)
#else
#define EXP2(x) exp2f(x)
#endif

// out: [0..3N) = -dH/dq = +400*sum_j K*(pi.pj)*(qi-qj); [3N..6N) = dH/dp = 2*sum_j K*pj
__global__ __launch_bounds__(BLOCK, 4) void lddmm_hamilton_kernel(
    const float* __restrict__ mom,  // [N,3]
    const float* __restrict__ q,    // [N,3]
    float* __restrict__ out)        // [2,N,3]
{
    // 24 KiB: first 1536 floats double as the j-stage (3 x 128 float4),
    // whole buffer later re-used as partial[4 waves][1536].
    __shared__ float lds[4 * 64 * IR * 6];

    float4* stA = (float4*)lds;          // (qx0,qx1,qy0,qy1) per pair
    float4* stB = stA + NPAIR;           // (qz0,qz1,px0,px1)
    float4* stC = stB + NPAIR;           // (py0,py1,pz0,pz1)

    const int tid = threadIdx.x;
    const int ib  = blockIdx.x & (NIB - 1);   // 0..31
    const int jsg = blockIdx.x >> 5;          // 0..31
    const int wv  = tid >> 6;                 // wave id = j-quarter
    const int il  = tid & 63;
    const int j0  = jsg * JBLK;

    // stage 256 j's as packed pairs (threads 0..127, coalesced 24B/lane reads)
    if (tid < NPAIR) {
        const float* qa = q   + 3 * (j0 + 2 * tid);  // qx0 qy0 qz0 qx1 qy1 qz1
        const float* pa = mom + 3 * (j0 + 2 * tid);
        stA[tid] = make_float4(qa[0], qa[3], qa[1], qa[4]);
        stB[tid] = make_float4(qa[2], qa[5], pa[0], pa[3]);
        stC[tid] = make_float4(pa[1], pa[4], pa[2], pa[5]);
    }

    // per-thread register tile of 4 i's
    float qi[IR][3], pi[IR][3];
    #pragma unroll
    for (int r = 0; r < IR; ++r) {
        const int i = ib * IBSZ + il + 64 * r;
        qi[r][0] = q[3*i+0];  qi[r][1] = q[3*i+1];  qi[r][2] = q[3*i+2];
        pi[r][0] = mom[3*i+0]; pi[r][1] = mom[3*i+1]; pi[r][2] = mom[3*i+2];
    }

    float aa[IR][3] = {{0}}, mm[IR][3] = {{0}};

    __syncthreads();

    const int p0 = wv * WPAIR;
    #pragma unroll 2
    for (int p = 0; p < WPAIR; ++p) {
        const float4 A = stA[p0 + p];    // wave-uniform broadcast ds_read_b128
        const float4 B = stB[p0 + p];
        const float4 C = stC[p0 + p];
        // j-even: q=(A.x,A.z,B.x) p=(B.z,C.x,C.z); j-odd: q=(A.y,A.w,B.y) p=(B.w,C.y,C.w)
        #pragma unroll
        for (int r = 0; r < IR; ++r) {
            {   // even j
                const float dx = qi[r][0] - A.x;
                const float dy = qi[r][1] - A.z;
                const float dz = qi[r][2] - B.x;
                const float d2 = dx*dx + dy*dy + dz*dz;
                const float K  = EXP2(d2 * NEG100_LOG2E);
                const float dt = pi[r][0]*B.z + pi[r][1]*C.x + pi[r][2]*C.z;
                mm[r][0] += K * B.z;  mm[r][1] += K * C.x;  mm[r][2] += K * C.z;
                const float w = K * dt;
                aa[r][0] += w * dx;   aa[r][1] += w * dy;   aa[r][2] += w * dz;
            }
            {   // odd j
                const float dx = qi[r][0] - A.y;
                const float dy = qi[r][1] - A.w;
                const float dz = qi[r][2] - B.y;
                const float d2 = dx*dx + dy*dy + dz*dz;
                const float K  = EXP2(d2 * NEG100_LOG2E);
                const float dt = pi[r][0]*B.w + pi[r][1]*C.y + pi[r][2]*C.w;
                mm[r][0] += K * B.w;  mm[r][1] += K * C.y;  mm[r][2] += K * C.w;
                const float w = K * dt;
                aa[r][0] += w * dx;   aa[r][1] += w * dy;   aa[r][2] += w * dz;
            }
        }
    }

    __syncthreads();   // all waves done reading the stage region

    // per-wave partials: pr[wv][ (il*IR + r)*6 + c ]
    #pragma unroll
    for (int r = 0; r < IR; ++r) {
        const int base = wv * 1536 + (il * IR + r) * 6;
        lds[base+0] = aa[r][0]; lds[base+1] = aa[r][1]; lds[base+2] = aa[r][2];
        lds[base+3] = mm[r][0]; lds[base+4] = mm[r][1]; lds[base+5] = mm[r][2];
    }
    __syncthreads();

    // cross-wave reduce: thread t owns (il2 = t>>2, r2 = t&3) -> 6 components
    {
        const int il2 = tid >> 2, r2 = tid & 3;
        const int i   = ib * IBSZ + il2 + 64 * r2;
        const int fb  = tid * 6;
        #pragma unroll
        for (int c = 0; c < 6; ++c) {
            const float s = lds[fb+c] + lds[1536+fb+c] + lds[3072+fb+c] + lds[4608+fb+c];
            if (c < 3) atomicAdd(&out[3*i + c],               400.0f * s);
            else       atomicAdd(&out[3*NPTS + 3*i + (c-3)],    2.0f * s);
        }
    }
}

extern "C" void kernel_launch(void* const* d_in, const int* in_sizes, int n_in,
                              void* d_out, int out_size, void* d_ws, size_t ws_size,
                              hipStream_t stream) {
    const float* mom = (const float*)d_in[0];   // setup_inputs order: mom first
    const float* q   = (const float*)d_in[1];   // then control_points
    float* out = (float*)d_out;

    // d_out is re-poisoned to 0xAA before every timed launch; atomics need zeros.
    hipMemsetAsync(out, 0, (size_t)out_size * sizeof(float), stream);

    const dim3 grid(NIB * JS);                  // 32*32 = 1024 blocks, 4/CU resident
    lddmm_hamilton_kernel<<<grid, BLOCK, 0, stream>>>(mom, q, out);
}